// Round 9
// baseline (99.482 us; speedup 1.0000x reference)
//
#include <hip/hip_runtime.h>
#include <hip/hip_bf16.h>

// Problem constants
#define NBATCH 256
#define NC 273     // C_IN (K)
#define ND 273     // C_OUT (M)
#define NT 360     // T (N)
#define NSUB 128

// GEMM tiling: one block = full D (288 padded) x 180 t-columns (2 tiles cover 360)
#define THREADS 512
#define BM 288
#define BN 192     // LDS cols (180 valid + 12 clamp-pad)
#define BNV 180
#define BK 32
#define LDK 40     // padded LDS row stride (elements) -> 80 B rows
#define KITERS 9   // ceil(273/32)

// wB: bf16 copy of w, SAME [S][C][D] layout (no transpose), in d_ws.
#define WB_ELEMS ((size_t)NSUB * NC * ND)      // 9,539,712
#define WB_BYTES (WB_ELEMS * 2 + 64)           // + slack

typedef __bf16 bf16_t;
typedef bf16_t bf16x4 __attribute__((ext_vector_type(4)));
typedef bf16_t bf16x8 __attribute__((ext_vector_type(8)));
typedef float  f32x4  __attribute__((ext_vector_type(4)));

// Raw barrier with NO vmcnt drain: LDS ops fenced manually with lgkmcnt(0);
// outstanding global loads stay in flight across the barrier.
#define LDS_FENCE_BARRIER()                                   \
    do {                                                      \
        asm volatile("s_waitcnt lgkmcnt(0)" ::: "memory");    \
        __builtin_amdgcn_s_barrier();                         \
    } while (0)

// ---- pre-pass: elementwise fp32 -> bf16 (same layout, fully coalesced) ----
__global__ __launch_bounds__(256) void conv_w(const float* __restrict__ w,
                                              bf16_t* __restrict__ wB) {
    const int n4 = (int)(WB_ELEMS / 4);  // 2,384,928 (divisible by 4)
    const int stride = gridDim.x * 256;
    for (int i = blockIdx.x * 256 + threadIdx.x; i < n4; i += stride) {
        f32x4 v = ((const f32x4*)w)[i];
        bf16x4 o;
#pragma unroll
        for (int u = 0; u < 4; ++u) o[u] = (bf16_t)v[u];
        ((bf16x4*)wB)[i] = o;
    }
}

// ---- main GEMM ----
template<bool BF16W>
__global__ __launch_bounds__(THREADS, 2) void subject_gemm(
    const float*  __restrict__ x,        // [B, C, T]
    const int*    __restrict__ subjects, // [B]
    const float*  __restrict__ w,        // [S, C, D] fp32 (fallback path)
    const bf16_t* __restrict__ wB,       // [S, C, D] bf16 (main path)
    float*        __restrict__ out)      // [B, D, T]
{
    // 512 blocks = 8 XCDs x 64 slots; keep a sample's 2 t-tiles on one XCD.
    const int raw  = blockIdx.x;
    const int xcd  = raw & 7;
    const int slot = raw >> 3;          // 0..63
    const int b    = xcd * 32 + (slot >> 1);
    const int tt   = slot & 1;
    const int t0   = tt * BNV;
    const int s    = subjects[b];

    const float*  __restrict__ xb  = x  + (size_t)b * NC * NT;
    const float*  __restrict__ wsf = w  + (size_t)s * NC * ND;
    const bf16_t* __restrict__ wsb = wB + (size_t)s * NC * ND;

    // Double-buffered LDS: 2 x (288*40 + 192*40) bf16 = 76800 B
    __shared__ __align__(16) bf16_t As[2][BM * LDK]; // [buf][d][k]
    __shared__ __align__(16) bf16_t Bs[2][BN * LDK]; // [buf][t][k]

    const int tid   = threadIdx.x;
    const int lane  = tid & 63;
    const int wid   = tid >> 6;   // 0..7
    const int wm    = wid >> 2;   // D half: 144 rows
    const int wn    = wid & 3;    // T quarter: 48 cols
    const int l16   = lane & 15;
    const int khalf = lane >> 4;  // 0..3

    // ---- staging coordinates (loop-invariant) ----
    // A: 2304 bf16x4-cells = (d 0..287 fast) x (kq 0..7); cell i = tid + 512*j
    //    j=0..3 full, j=4 only tid<256. Lanes -> consecutive d = coalesced rows.
    int offA[5], gA[5], dA[5], cqA[5];
#pragma unroll
    for (int j = 0; j < 5; ++j) {
        const int i  = tid + THREADS * j;
        const int ii = (i < 2304) ? i : 2303;
        const int d  = ii % BM;
        const int kq = ii / BM;
        offA[j] = d * LDK + kq * 4;
        gA[j]   = (kq * 4) * ND + d;   // + kk*ND + u*ND at load time
        dA[j]   = d;
        cqA[j]  = kq * 4;
    }
    // B: 1536 cells = (t 0..191 fast) x (kq 0..7); i = tid + 512*j, j=0..2 exact
    int offB[3], gB[3];
#pragma unroll
    for (int j = 0; j < 3; ++j) {
        const int i  = tid + THREADS * j;
        const int t  = i % BN;
        const int kq = i / BN;
        const int tc = (t < BNV) ? t : (BNV - 1);   // clamp pad cols (masked at store)
        offB[j] = t * LDK + kq * 4;
        gB[j]   = kq * 4 * NT + t0 + tc;
    }
    const bool haveJ4 = (tid < 2304 - 4 * THREADS); // tid < 256, wave-uniform

    // NAMED depth-2 staging sets (even/odd tiles) -- never runtime-indexed.
    bf16x4 aEv[5], aOd[5];
    float  bEv[3][4], bOd[3][4];

    // A loads. Non-tail (kk<=224): unmasked — max flat idx (255)*273+287 < 273*273,
    // stays inside W[s]; pad-row values are garbage masked at the store.
    auto loadA = [&](bf16x4 (&r)[5], int kk) {
        if constexpr (BF16W) {
            const int base = kk * ND;
#pragma unroll
            for (int j = 0; j < 4; ++j) {
                bf16x4 v;
#pragma unroll
                for (int u = 0; u < 4; ++u) v[u] = wsb[base + gA[j] + u * ND];
                r[j] = v;
            }
            if (haveJ4) {
                bf16x4 v;
#pragma unroll
                for (int u = 0; u < 4; ++u) v[u] = wsb[base + gA[4] + u * ND];
                r[4] = v;
            }
        } else {
            // fallback fp32 path: masked everywhere (perf-irrelevant)
#pragma unroll
            for (int j = 0; j < 5; ++j) {
                if (j == 4 && !haveJ4) break;
                bf16x4 v;
#pragma unroll
                for (int u = 0; u < 4; ++u) {
                    const int c = kk + cqA[j] + u;
                    const float f = (c < NC && dA[j] < ND) ? wsf[c * ND + dA[j]] : 0.f;
                    v[u] = (bf16_t)f;
                }
                r[j] = v;
            }
        }
    };
    // Tail (kk=256): c in [256,288) -> ZERO where c>=273 or d>=273
    // (A zeros kill B-tail garbage).
    auto loadA_tail = [&](bf16x4 (&r)[5]) {
#pragma unroll
        for (int j = 0; j < 5; ++j) {
            if (j == 4 && !haveJ4) break;
            bf16x4 v;
#pragma unroll
            for (int u = 0; u < 4; ++u) {
                const int c = 256 + cqA[j] + u;
                const bool ok = (c < NC) && (dA[j] < ND);
                if constexpr (BF16W)
                    v[u] = ok ? wsb[c * ND + dA[j]] : (bf16_t)0.f;
                else
                    v[u] = ok ? (bf16_t)wsf[c * ND + dA[j]] : (bf16_t)0.f;
            }
            r[j] = v;
        }
    };
    auto loadB = [&](float (&r)[3][4], int kk) {
        const int base = kk * NT;
#pragma unroll
        for (int j = 0; j < 3; ++j)
#pragma unroll
            for (int u = 0; u < 4; ++u)
                r[j][u] = xb[base + gB[j] + u * NT];
    };
    auto loadB_tail = [&](float (&r)[3][4]) {
#pragma unroll
        for (int j = 0; j < 3; ++j) {
            const int i  = tid + THREADS * j;
            const int t  = i % BN;
            const int kq = i / BN;
            const int col = t0 + ((t < BNV) ? t : (BNV - 1));
#pragma unroll
            for (int u = 0; u < 4; ++u) {
                const int c  = 256 + kq * 4 + u;
                const int cc = (c < NC) ? c : (NC - 1);  // clamp addr; killed by A zeros
                r[j][u] = xb[cc * NT + col];
            }
        }
    };
    auto stage = [&](const bf16x4 (&rA)[5], const float (&rB)[3][4],
                     bf16_t* dA_, bf16_t* dB_) {
#pragma unroll
        for (int j = 0; j < 4; ++j)
            *(bf16x4*)&dA_[offA[j]] = rA[j];
        if (haveJ4)
            *(bf16x4*)&dA_[offA[4]] = rA[4];
#pragma unroll
        for (int j = 0; j < 3; ++j) {
            bf16x4 v;
#pragma unroll
            for (int u = 0; u < 4; ++u) v[u] = (bf16_t)rB[j][u];
            *(bf16x4*)&dB_[offB[j]] = v;
        }
    };

    f32x4 acc[9][3];
#pragma unroll
    for (int m = 0; m < 9; ++m)
#pragma unroll
        for (int n = 0; n < 3; ++n)
            acc[m][n] = (f32x4){0.f, 0.f, 0.f, 0.f};

    // ---- prologue: tiles 0 (->Ev) and 1 (->Od) in flight; tile 0 staged ----
    loadA(aEv, 0);       loadB(bEv, 0);
    loadA(aOd, BK);      loadB(bOd, BK);
    stage(aEv, bEv, &As[0][0], &Bs[0][0]);   // counted vmcnt: tile1 stays in flight
    LDS_FENCE_BARRIER();

    // ---- main loop, manually unrolled x2 (static buffer choice) ----
#pragma unroll
    for (int p = 0; p < 4; ++p) {
        {   // even iter it0 = 2p: reads LDS0, stages Od -> LDS1
            const int it0 = 2 * p;
            bf16x8 af[9], bfr[3];
#pragma unroll
            for (int n = 0; n < 3; ++n)
                bfr[n] = *(const bf16x8*)&Bs[0][(wn * 48 + n * 16 + l16) * LDK + khalf * 8];
#pragma unroll
            for (int m = 0; m < 9; ++m)
                af[m] = *(const bf16x8*)&As[0][(wm * 144 + m * 16 + l16) * LDK + khalf * 8];

            // prefetch even tile it0+2 into Ev (it0+2 in {2,4,6,8}; 8 = tail)
            if (it0 + 2 <= KITERS - 2) {
                loadA(aEv, (it0 + 2) * BK);
                loadB(bEv, (it0 + 2) * BK);
            } else {                     // it0+2 == 8
                loadA_tail(aEv);
                loadB_tail(bEv);
            }
            stage(aOd, bOd, &As[1][0], &Bs[1][0]);
            LDS_FENCE_BARRIER();

#pragma unroll
            for (int m = 0; m < 9; ++m)
#pragma unroll
                for (int n = 0; n < 3; ++n)
                    acc[m][n] = __builtin_amdgcn_mfma_f32_16x16x32_bf16(af[m], bfr[n], acc[m][n], 0, 0, 0);
        }
        {   // odd iter it1 = 2p+1: reads LDS1, stages Ev -> LDS0
            const int it1 = 2 * p + 1;
            bf16x8 af[9], bfr[3];
#pragma unroll
            for (int n = 0; n < 3; ++n)
                bfr[n] = *(const bf16x8*)&Bs[1][(wn * 48 + n * 16 + l16) * LDK + khalf * 8];
#pragma unroll
            for (int m = 0; m < 9; ++m)
                af[m] = *(const bf16x8*)&As[1][(wm * 144 + m * 16 + l16) * LDK + khalf * 8];

            // prefetch odd tile it1+2 into Od (it1+2 in {3,5,7,9}; 9 -> none)
            if (it1 + 2 <= KITERS - 2) {
                loadA(aOd, (it1 + 2) * BK);
                loadB(bOd, (it1 + 2) * BK);
            }
            stage(aEv, bEv, &As[0][0], &Bs[0][0]);
            LDS_FENCE_BARRIER();

#pragma unroll
            for (int m = 0; m < 9; ++m)
#pragma unroll
                for (int n = 0; n < 3; ++n)
                    acc[m][n] = __builtin_amdgcn_mfma_f32_16x16x32_bf16(af[m], bfr[n], acc[m][n], 0, 0, 0);
        }
    }
    {   // final iter (it = 8, even): tile 8 is in LDS0
        bf16x8 af[9], bfr[3];
#pragma unroll
        for (int n = 0; n < 3; ++n)
            bfr[n] = *(const bf16x8*)&Bs[0][(wn * 48 + n * 16 + l16) * LDK + khalf * 8];
#pragma unroll
        for (int m = 0; m < 9; ++m)
            af[m] = *(const bf16x8*)&As[0][(wm * 144 + m * 16 + l16) * LDK + khalf * 8];
#pragma unroll
        for (int m = 0; m < 9; ++m)
#pragma unroll
            for (int n = 0; n < 3; ++n)
                acc[m][n] = __builtin_amdgcn_mfma_f32_16x16x32_bf16(af[m], bfr[n], acc[m][n], 0, 0, 0);
    }

    // Epilogue: C/D layout col(t)=lane&15, row(d)=(lane>>4)*4+reg (verified R1-R8)
    float* __restrict__ ob = out + (size_t)b * ND * NT;
#pragma unroll
    for (int m = 0; m < 9; ++m) {
#pragma unroll
        for (int n = 0; n < 3; ++n) {
            const int tc = wn * 48 + n * 16 + l16;
            const int gt = t0 + tc;
#pragma unroll
            for (int rg = 0; rg < 4; ++rg) {
                const int d = wm * 144 + m * 16 + khalf * 4 + rg;
                if (d < ND && tc < BNV)
                    ob[(size_t)d * NT + gt] = acc[m][n][rg];
            }
        }
    }
}

extern "C" void kernel_launch(void* const* d_in, const int* in_sizes, int n_in,
                              void* d_out, int out_size, void* d_ws, size_t ws_size,
                              hipStream_t stream) {
    const float* x        = (const float*)d_in[0];
    const int*   subjects = (const int*)d_in[1];
    const float* w        = (const float*)d_in[2];
    float*       out      = (float*)d_out;
    bf16_t*      wB       = (bf16_t*)d_ws;

    const int nblocks = NBATCH * 2; // 512 = 8 XCDs * 64; 2 t-tiles per sample

    if (ws_size >= WB_BYTES) {
        conv_w<<<2048, 256, 0, stream>>>(w, wB);
        subject_gemm<true><<<nblocks, THREADS, 0, stream>>>(x, subjects, w, wB, out);
    } else {
        subject_gemm<false><<<nblocks, THREADS, 0, stream>>>(x, subjects, w, wB, out);
    }
}

// Round 10
// 70.199 us; speedup vs baseline: 1.4171x; 1.4171x over previous
//
#include <hip/hip_runtime.h>
#include <hip/hip_bf16.h>

// Problem constants
#define NBATCH 256
#define NC 273     // C_IN (K)
#define ND 273     // C_OUT (M)
#define NT 360     // T (N)
#define NSUB 128

// GEMM tiling: one block = full D (288 padded) x 192 t-columns.
// Asymmetric t-split: tile0 = t[0,192) full, tile1 = t[192,360) = 168 valid.
// Both store bases (0 B, 768 B) are 64-B aligned -> no straddled store lines.
#define THREADS 512
#define BM 288
#define BN 192
#define BK 32
#define LDK 40     // padded LDS row stride (elements) -> 80 B rows
#define KITERS 9   // ceil(273/32)

// wT (bf16, transposed w) layout in d_ws: [NSUB][288 d-rows][288 c-cols]
// c in [273,288) zero-filled for d<273 -> GEMM K-tail needs no masking.
#define WT_LD 288
#define WT_SUBJ (288 * 288)
#define WT_BYTES ((size_t)NSUB * WT_SUBJ * 2)

typedef __bf16 bf16_t;
typedef bf16_t bf16x4 __attribute__((ext_vector_type(4)));
typedef bf16_t bf16x8 __attribute__((ext_vector_type(8)));
typedef float  f32x4  __attribute__((ext_vector_type(4)));

// Raw barrier with NO vmcnt drain: LDS ops fenced manually with lgkmcnt(0);
// outstanding global loads stay in flight across the barrier.
#define LDS_FENCE_BARRIER()                                   \
    do {                                                      \
        asm volatile("s_waitcnt lgkmcnt(0)" ::: "memory");    \
        __builtin_amdgcn_s_barrier();                         \
    } while (0)

// ---- pre-pass: w[s][c][d] fp32 -> wT[s][d][c] bf16 (LDS-tiled transpose) ----
// (R8-proven: zero-fills c in [273,288) for d<273.)
__global__ __launch_bounds__(256) void conv_w(const float* __restrict__ w,
                                              bf16_t* __restrict__ wT) {
    const int bid  = blockIdx.x;       // 128 subjects x 25 tiles
    const int s    = bid / 25;
    const int tile = bid % 25;
    const int c0   = (tile / 5) * 64;
    const int d0   = (tile % 5) * 64;
    const int tx   = threadIdx.x & 63;
    const int ty   = threadIdx.x >> 6; // 0..3

    __shared__ float t[64][65];
    const float* __restrict__ wsrc = w + (size_t)s * NC * ND;
#pragma unroll
    for (int j = 0; j < 16; ++j) {
        const int row = ty + j * 4;           // c-local
        const int c = c0 + row, d = d0 + tx;  // read coalesced along d
        t[row][tx] = (c < NC && d < ND) ? wsrc[c * ND + d] : 0.f;
    }
    __syncthreads();
    bf16_t* __restrict__ wdst = wT + (size_t)s * WT_SUBJ;
#pragma unroll
    for (int j = 0; j < 16; ++j) {
        const int row = ty + j * 4;           // d-local
        const int d = d0 + row, c = c0 + tx;  // write coalesced along c
        if (d < ND && c < WT_LD)
            wdst[d * WT_LD + c] = (bf16_t)t[tx][row];
    }
}

// ---- main GEMM ----
template<bool BF16W>
__global__ __launch_bounds__(THREADS, 2) void subject_gemm(
    const float*  __restrict__ x,        // [B, C, T]
    const int*    __restrict__ subjects, // [B]
    const float*  __restrict__ w,        // [S, C, D] fp32 (fallback path)
    const bf16_t* __restrict__ wT,       // [S, 288, 288] bf16 (main path)
    float*        __restrict__ out)      // [B, D, T]
{
    // 512 blocks = 8 XCDs x 64 slots; keep a sample's 2 t-tiles on one XCD.
    const int raw  = blockIdx.x;
    const int xcd  = raw & 7;
    const int slot = raw >> 3;          // 0..63
    const int b    = xcd * 32 + (slot >> 1);
    const int tt   = slot & 1;
    const int t0   = tt * BN;           // 0 or 192 -> 0 B / 768 B (64-B aligned)
    const int bnv  = tt ? (NT - BN) : BN;  // 168 or 192 valid columns
    const int s    = subjects[b];

    const float*  __restrict__ xb  = x  + (size_t)b * NC * NT;
    const float*  __restrict__ wsf = w  + (size_t)s * NC * ND;
    const bf16_t* __restrict__ wsb = wT + (size_t)s * WT_SUBJ;

    // Double-buffered LDS: 2 x (288*40 + 192*40) bf16 = 76800 B
    __shared__ __align__(16) bf16_t As[2][BM * LDK]; // [buf][d][k]
    __shared__ __align__(16) bf16_t Bs[2][BN * LDK]; // [buf][t][k]

    const int tid   = threadIdx.x;
    const int lane  = tid & 63;
    const int wid   = tid >> 6;   // 0..7
    const int wm    = wid >> 2;   // D half: 144 rows
    const int wn    = wid & 3;    // T quarter: 48 cols
    const int l16   = lane & 15;
    const int khalf = lane >> 4;  // 0..3

    // A: 2304 bf16x4-cells; cell i = tid + 512*j: kq = i&7 (fast), d = i>>3
    // -> 8-B loads, 8 lanes cover one contiguous 64-B wT row chunk.
    int offA[5], gA[5], dA[5], cqA[5];
#pragma unroll
    for (int j = 0; j < 5; ++j) {
        const int i  = tid + THREADS * j;
        const int ii = (i < 2304) ? i : 2303;
        const int kq = ii & 7;
        const int d  = ii >> 3;
        offA[j] = d * LDK + kq * 4;
        gA[j]   = d * WT_LD + kq * 4;  // + kk at load time (bf16 elems)
        dA[j]   = d;
        cqA[j]  = kq * 4;
    }
    // B: 1536 cells = (t 0..191 fast) x (kq 0..7); i = tid + 512*j, j=0..2 exact
    int offB[3], gB[3];
#pragma unroll
    for (int j = 0; j < 3; ++j) {
        const int i  = tid + THREADS * j;
        const int t  = i % BN;
        const int kq = i / BN;
        const int tc = (t < bnv) ? t : (bnv - 1);   // clamp pad cols (masked at store)
        offB[j] = t * LDK + kq * 4;
        gB[j]   = kq * 4 * NT + t0 + tc;
    }
    const bool haveJ4 = (tid < 2304 - 4 * THREADS); // tid < 256, wave-uniform

    // NAMED depth-2 staging sets (even/odd tiles) -- never runtime-indexed.
    bf16x4 aEv[5], aOd[5];
    float  bEv[3][4], bOd[3][4];

    // A load (bf16 path): unmasked for ALL tiles incl. K-tail — c <= 287 < 288
    // stays in-row; c-pad zeros kill the K-tail; d-pad rows masked at store.
    auto loadA = [&](bf16x4 (&r)[5], int kk) {
        if constexpr (BF16W) {
#pragma unroll
            for (int j = 0; j < 4; ++j)
                r[j] = *(const bf16x4*)&wsb[gA[j] + kk];
            if (haveJ4)
                r[4] = *(const bf16x4*)&wsb[gA[4] + kk];
        } else {
            // fallback fp32 path: masked everywhere (perf-irrelevant)
#pragma unroll
            for (int j = 0; j < 5; ++j) {
                if (j == 4 && !haveJ4) break;
                bf16x4 v;
#pragma unroll
                for (int u = 0; u < 4; ++u) {
                    const int c = kk + cqA[j] + u;
                    const float f = (c < NC && dA[j] < ND) ? wsf[c * ND + dA[j]] : 0.f;
                    v[u] = (bf16_t)f;
                }
                r[j] = v;
            }
        }
    };
    auto loadB = [&](float (&r)[3][4], int kk) {
        const int base = kk * NT;
#pragma unroll
        for (int j = 0; j < 3; ++j)
#pragma unroll
            for (int u = 0; u < 4; ++u)
                r[j][u] = xb[base + gB[j] + u * NT];
    };
    // B tail (kk=256): clamp c addr; garbage killed by A's zero c-pad.
    auto loadB_tail = [&](float (&r)[3][4]) {
#pragma unroll
        for (int j = 0; j < 3; ++j) {
#pragma unroll
            for (int u = 0; u < 4; ++u) {
                const int c  = 256 + (gB[j] / NT) /*kq*4*/ + u;  // note: gB[j]/NT == kq*4
                const int cc = (c < NC) ? c : (NC - 1);
                r[j][u] = xb[cc * NT + (gB[j] % NT)];
            }
        }
    };
    auto stage = [&](const bf16x4 (&rA)[5], const float (&rB)[3][4],
                     bf16_t* dA_, bf16_t* dB_) {
#pragma unroll
        for (int j = 0; j < 4; ++j)
            *(bf16x4*)&dA_[offA[j]] = rA[j];
        if (haveJ4)
            *(bf16x4*)&dA_[offA[4]] = rA[4];
#pragma unroll
        for (int j = 0; j < 3; ++j) {
            bf16x4 v;
#pragma unroll
            for (int u = 0; u < 4; ++u) v[u] = (bf16_t)rB[j][u];
            *(bf16x4*)&dB_[offB[j]] = v;
        }
    };

    f32x4 acc[9][3];
#pragma unroll
    for (int m = 0; m < 9; ++m)
#pragma unroll
        for (int n = 0; n < 3; ++n)
            acc[m][n] = (f32x4){0.f, 0.f, 0.f, 0.f};

    // ---- prologue: tiles 0 (->Ev) and 1 (->Od) in flight; tile 0 staged ----
    loadA(aEv, 0);       loadB(bEv, 0);
    loadA(aOd, BK);      loadB(bOd, BK);
    stage(aEv, bEv, &As[0][0], &Bs[0][0]);   // counted vmcnt: tile1 stays in flight
    LDS_FENCE_BARRIER();

    // ---- main loop, manually unrolled x2 (static buffer choice) ----
#pragma unroll
    for (int p = 0; p < 4; ++p) {
        {   // even iter it0 = 2p: reads LDS0, stages Od -> LDS1
            const int it0 = 2 * p;
            bf16x8 af[9], bfr[3];
#pragma unroll
            for (int n = 0; n < 3; ++n)
                bfr[n] = *(const bf16x8*)&Bs[0][(wn * 48 + n * 16 + l16) * LDK + khalf * 8];
#pragma unroll
            for (int m = 0; m < 9; ++m)
                af[m] = *(const bf16x8*)&As[0][(wm * 144 + m * 16 + l16) * LDK + khalf * 8];

            // prefetch even tile it0+2 into Ev (it0+2 in {2,4,6,8}; 8 = K-tail)
            if (it0 + 2 <= KITERS - 2) {
                loadA(aEv, (it0 + 2) * BK);
                loadB(bEv, (it0 + 2) * BK);
            } else {                     // it0+2 == 8: A unmasked (zero c-pad), B clamped
                loadA(aEv, 256);
                loadB_tail(bEv);
            }
            stage(aOd, bOd, &As[1][0], &Bs[1][0]);
            LDS_FENCE_BARRIER();

#pragma unroll
            for (int m = 0; m < 9; ++m)
#pragma unroll
                for (int n = 0; n < 3; ++n)
                    acc[m][n] = __builtin_amdgcn_mfma_f32_16x16x32_bf16(af[m], bfr[n], acc[m][n], 0, 0, 0);
        }
        {   // odd iter it1 = 2p+1: reads LDS1, stages Ev -> LDS0
            const int it1 = 2 * p + 1;
            bf16x8 af[9], bfr[3];
#pragma unroll
            for (int n = 0; n < 3; ++n)
                bfr[n] = *(const bf16x8*)&Bs[1][(wn * 48 + n * 16 + l16) * LDK + khalf * 8];
#pragma unroll
            for (int m = 0; m < 9; ++m)
                af[m] = *(const bf16x8*)&As[1][(wm * 144 + m * 16 + l16) * LDK + khalf * 8];

            // prefetch odd tile it1+2 into Od (it1+2 in {3,5,7,9}; 9 -> none)
            if (it1 + 2 <= KITERS - 2) {
                loadA(aOd, (it1 + 2) * BK);
                loadB(bOd, (it1 + 2) * BK);
            }
            stage(aEv, bEv, &As[0][0], &Bs[0][0]);
            LDS_FENCE_BARRIER();

#pragma unroll
            for (int m = 0; m < 9; ++m)
#pragma unroll
                for (int n = 0; n < 3; ++n)
                    acc[m][n] = __builtin_amdgcn_mfma_f32_16x16x32_bf16(af[m], bfr[n], acc[m][n], 0, 0, 0);
        }
    }
    {   // final iter (it = 8, even): tile 8 is in LDS0
        bf16x8 af[9], bfr[3];
#pragma unroll
        for (int n = 0; n < 3; ++n)
            bfr[n] = *(const bf16x8*)&Bs[0][(wn * 48 + n * 16 + l16) * LDK + khalf * 8];
#pragma unroll
        for (int m = 0; m < 9; ++m)
            af[m] = *(const bf16x8*)&As[0][(wm * 144 + m * 16 + l16) * LDK + khalf * 8];
#pragma unroll
        for (int m = 0; m < 9; ++m)
#pragma unroll
            for (int n = 0; n < 3; ++n)
                acc[m][n] = __builtin_amdgcn_mfma_f32_16x16x32_bf16(af[m], bfr[n], acc[m][n], 0, 0, 0);
    }

    // Epilogue: C/D layout col(t)=lane&15, row(d)=(lane>>4)*4+reg (verified R1-R9).
    // All store bases 64-B aligned: (t0 + wn*48 + n*16)*4 ≡ 0 mod 64.
    float* __restrict__ ob = out + (size_t)b * ND * NT;
#pragma unroll
    for (int m = 0; m < 9; ++m) {
#pragma unroll
        for (int n = 0; n < 3; ++n) {
            const int tc = wn * 48 + n * 16 + l16;
            const int gt = t0 + tc;
#pragma unroll
            for (int rg = 0; rg < 4; ++rg) {
                const int d = wm * 144 + m * 16 + khalf * 4 + rg;
                if (d < ND && tc < bnv)
                    ob[(size_t)d * NT + gt] = acc[m][n][rg];
            }
        }
    }
}

extern "C" void kernel_launch(void* const* d_in, const int* in_sizes, int n_in,
                              void* d_out, int out_size, void* d_ws, size_t ws_size,
                              hipStream_t stream) {
    const float* x        = (const float*)d_in[0];
    const int*   subjects = (const int*)d_in[1];
    const float* w        = (const float*)d_in[2];
    float*       out      = (float*)d_out;
    bf16_t*      wT       = (bf16_t*)d_ws;

    const int nblocks = NBATCH * 2; // 512 = 8 XCDs * 64; 2 t-tiles per sample

    if (ws_size >= WT_BYTES) {
        conv_w<<<NSUB * 25, 256, 0, stream>>>(w, wT);
        subject_gemm<true><<<nblocks, THREADS, 0, stream>>>(x, subjects, w, wT, out);
    } else {
        subject_gemm<false><<<nblocks, THREADS, 0, stream>>>(x, subjects, w, wT, out);
    }
}